// Round 1
// baseline (16159.457 us; speedup 1.0000x reference)
//
#include <hip/hip_runtime.h>

// RNNModule: leaky ReLU RNN scan + output projection, MI355X (gfx950).
//
// states[b,0,:]=0 ; for s=1..749: h = 0.8*h + 0.2*relu(h@w_rec^T + u[.,s-1]@w_in^T + noise[.,s-1])
// out = states @ w_out^T ; outputs = (states, out[:,mask,:], out)
//
// Strategy: 16 independent batch-groups (16 rows each) x 16 blocks (32-neuron slice,
// w_rec slice bf16 in LDS). Per-group monotonic-counter barrier; h exchanged via
// double-buffered bf16 buffer in d_ws. bf16 MFMA 16x16x32, fp32 state in registers.

typedef __attribute__((ext_vector_type(4))) float f32x4;
typedef __attribute__((ext_vector_type(8))) short s16x8;

#define ALPHA_ 0.2f
constexpr int BB = 256, TT = 750, NN = 512, INN = 6, OUTN = 2, MLEN = 250;
constexpr int BBLK = 16;              // batch rows per group
constexpr int NSLC = 32;              // neuron cols per block
constexpr int NGRP = BB / BBLK;       // 16 groups
constexpr int NBLK = NN / NSLC;       // 16 blocks per group
constexpr int NBLOCKS = NGRP * NBLK;  // 256 blocks, 1 wave each

__device__ __forceinline__ unsigned short f2bf(float f) {
    unsigned int v = __float_as_uint(f);
    v += 0x7fffu + ((v >> 16) & 1u);            // round-to-nearest-even
    return (unsigned short)(v >> 16);
}

__global__ void init_kernel(int* cnts) {
    for (int i = threadIdx.x; i < NGRP * 32; i += blockDim.x) cnts[i] = 0;
}

__global__ __launch_bounds__(64)
void rnn_scan_kernel(const float* __restrict__ u, const float* __restrict__ noise,
                     const float* __restrict__ w_rec, const float* __restrict__ w_in,
                     float* __restrict__ states, unsigned short* __restrict__ hbuf,
                     int* __restrict__ cnts)
{
    const int lane = threadIdx.x;                 // 0..63, one wave per block
    const int bid  = blockIdx.x;
    // group-mates share blockIdx%8 (XCD round-robin heuristic; correctness-neutral)
    const int c  = bid & 7, q2 = bid >> 3;        // q2: 0..31
    const int g  = c * 2 + (q2 & 1);              // group 0..15
    const int j  = q2 >> 1;                       // block-in-group 0..15
    const int bg = g * BBLK, nj = j * NSLC;
    const int qq = lane >> 4, lr = lane & 15;

    __shared__ unsigned short wlds[NSLC * NN];    // 32 KB, bf16, XOR-swizzled 16B slots

    // one-time: stage w_rec rows [nj, nj+32) into LDS (swizzle: slot ^= row&7)
    for (int idx = lane; idx < NSLC * NN; idx += 64) {
        int row = idx >> 9, k = idx & 511;
        float wv = w_rec[(size_t)(nj + row) * NN + k];
        int sl = k >> 3;
        wlds[(row << 9) + (((sl ^ (row & 7)) << 3) | (k & 7))] = f2bf(wv);
    }
    // per-lane w_in slice: n = nj + 16*tt + lr
    float wi[2][INN];
    #pragma unroll
    for (int tt = 0; tt < 2; ++tt) {
        int n = nj + 16 * tt + lr;
        #pragma unroll
        for (int i = 0; i < INN; ++i) wi[tt][i] = w_in[n * INN + i];
    }
    __syncthreads();

    float st[2][4];                               // h_old tile, D-fragment layout
    #pragma unroll
    for (int tt = 0; tt < 2; ++tt)
        #pragma unroll
        for (int r = 0; r < 4; ++r) st[tt][r] = 0.f;

    // phase 0: zero own slice of states[:,0,:] and hbuf[0], then arrive
    #pragma unroll
    for (int tt = 0; tt < 2; ++tt)
        #pragma unroll
        for (int r = 0; r < 4; ++r) {
            int b = bg + 4 * qq + r, n = nj + 16 * tt + lr;
            states[(size_t)b * TT * NN + n] = 0.f;
            hbuf[(size_t)b * NN + n] = 0;         // bf16 +0
        }
    __threadfence();
    if (lane == 0)
        __hip_atomic_fetch_add(&cnts[g * 32], 1, __ATOMIC_RELEASE, __HIP_MEMORY_SCOPE_AGENT);

    for (int s = 1; s < TT; ++s) {
        // drive loads (input-only: safe to issue before the barrier, hides latency)
        float uu[4][INN], nz[2][4];
        #pragma unroll
        for (int r = 0; r < 4; ++r) {
            const float* up = u + ((size_t)(bg + 4 * qq + r) * TT + (s - 1)) * INN;
            #pragma unroll
            for (int i = 0; i < INN; ++i) uu[r][i] = up[i];
        }
        #pragma unroll
        for (int tt = 0; tt < 2; ++tt)
            #pragma unroll
            for (int r = 0; r < 4; ++r)
                nz[tt][r] = noise[((size_t)(bg + 4 * qq + r) * TT + (s - 1)) * NN
                                  + (nj + 16 * tt + lr)];

        // group barrier: wait for all 16 blocks to have finished phase s-1
        const int target = NBLK * s;
        if (lane == 0) {
            while (__hip_atomic_load(&cnts[g * 32], __ATOMIC_ACQUIRE,
                                     __HIP_MEMORY_SCOPE_AGENT) < target) {}
        }
        __threadfence();                          // wave-wide acquire (invalidate)

        // A-fragments: h_{s-1} rows bg..bg+15 from global double buffer
        const unsigned short* hrow = hbuf + (size_t)((s - 1) & 1) * BB * NN
                                     + (size_t)(bg + lr) * NN + qq * 8;
        s16x8 afr[16];
        #pragma unroll
        for (int kk = 0; kk < 16; ++kk)
            afr[kk] = *(const s16x8*)(hrow + kk * 32);

        // MFMA: two 16x16 n-tiles, K=512 (16 steps of k=32)
        f32x4 acc[2];
        #pragma unroll
        for (int tt = 0; tt < 2; ++tt) {
            const int row = 16 * tt + lr;
            const unsigned short* wr = wlds + (row << 9);
            const int rx = row & 7;
            f32x4 a = {0.f, 0.f, 0.f, 0.f};
            #pragma unroll
            for (int kk = 0; kk < 16; ++kk) {
                s16x8 bfr = *(const s16x8*)(wr + (((kk * 4 + qq) ^ rx) << 3));
                a = __builtin_amdgcn_mfma_f32_16x16x32_bf16(afr[kk], bfr, a, 0, 0, 0);
            }
            acc[tt] = a;
        }

        // epilogue: drive + leaky relu update; write states (fp32) + hbuf (bf16)
        unsigned short* hw = hbuf + (size_t)(s & 1) * BB * NN;
        #pragma unroll
        for (int tt = 0; tt < 2; ++tt)
            #pragma unroll
            for (int r = 0; r < 4; ++r) {
                float pre = acc[tt][r] + nz[tt][r];
                #pragma unroll
                for (int i = 0; i < INN; ++i) pre += uu[r][i] * wi[tt][i];
                float hn = (1.f - ALPHA_) * st[tt][r] + ALPHA_ * fmaxf(pre, 0.f);
                st[tt][r] = hn;
                int b = bg + 4 * qq + r, n = nj + 16 * tt + lr;
                states[((size_t)b * TT + s) * NN + n] = hn;
                hw[(size_t)b * NN + n] = f2bf(hn);
            }
        __threadfence();
        if (lane == 0)
            __hip_atomic_fetch_add(&cnts[g * 32], 1, __ATOMIC_RELEASE,
                                   __HIP_MEMORY_SCOPE_AGENT);
    }
}

// out[b,t,o] = sum_n states[b,t,n] * w_out[o,n]; one wave per (b,t) row
__global__ __launch_bounds__(256)
void proj_kernel(const float* __restrict__ states, const float* __restrict__ w_out,
                 float* __restrict__ outf)
{
    const int wv   = (blockIdx.x * blockDim.x + threadIdx.x) >> 6;  // row id, exact grid
    const int lane = threadIdx.x & 63;
    const float* sp = states + (size_t)wv * NN + lane * 8;
    const float* w0 = w_out + lane * 8;
    const float* w1 = w_out + NN + lane * 8;
    float d0 = 0.f, d1 = 0.f;
    #pragma unroll
    for (int i = 0; i < 8; ++i) {
        float sv = sp[i];
        d0 += sv * w0[i];
        d1 += sv * w1[i];
    }
    #pragma unroll
    for (int off = 32; off > 0; off >>= 1) {
        d0 += __shfl_xor(d0, off);
        d1 += __shfl_xor(d1, off);
    }
    if (lane == 0) {
        outf[(size_t)wv * 2]     = d0;
        outf[(size_t)wv * 2 + 1] = d1;
    }
}

__global__ void mask_kernel(const int* __restrict__ mask, const float* __restrict__ outf,
                            float* __restrict__ outm)
{
    int idx = blockIdx.x * blockDim.x + threadIdx.x;
    if (idx >= BB * MLEN * OUTN) return;
    int o  = idx % OUTN;
    int jm = (idx / OUTN) % MLEN;
    int b  = idx / (OUTN * MLEN);
    int t  = mask[jm];
    outm[idx] = outf[((size_t)b * TT + t) * OUTN + o];
}

extern "C" void kernel_launch(void* const* d_in, const int* in_sizes, int n_in,
                              void* d_out, int out_size, void* d_ws, size_t ws_size,
                              hipStream_t stream)
{
    (void)in_sizes; (void)n_in; (void)out_size; (void)ws_size;
    const float* u     = (const float*)d_in[0];
    const float* noise = (const float*)d_in[1];
    const float* w_rec = (const float*)d_in[2];
    const float* w_in  = (const float*)d_in[3];
    const float* w_out = (const float*)d_in[4];
    const int*   mask  = (const int*)d_in[5];

    float* states = (float*)d_out;                          // [256][750][512]
    float* outm   = states + (size_t)BB * TT * NN;          // [256][250][2]
    float* outf   = outm + (size_t)BB * MLEN * OUTN;        // [256][750][2]

    int* cnts = (int*)d_ws;                                 // 16 groups x 128B lines
    unsigned short* hbuf = (unsigned short*)((char*)d_ws + 4096);  // 2 x [256][512] bf16

    init_kernel<<<1, 256, 0, stream>>>(cnts);
    rnn_scan_kernel<<<NBLOCKS, 64, 0, stream>>>(u, noise, w_rec, w_in, states, hbuf, cnts);
    proj_kernel<<<(BB * TT) / 4, 256, 0, stream>>>(states, w_out, outf);
    mask_kernel<<<(BB * MLEN * OUTN + 255) / 256, 256, 0, stream>>>(mask, outf, outm);
}

// Round 2
// 2591.200 us; speedup vs baseline: 6.2363x; 6.2363x over previous
//
#include <hip/hip_runtime.h>

// RNNModule: leaky ReLU RNN scan + output projection, MI355X (gfx950).
// r2: single-CU batch groups (8 waves, weights register/LDS-resident),
//     LDS-only h exchange with lgkm-only barriers, precomputed bf16 drive.

typedef __attribute__((ext_vector_type(4))) float f32x4;
typedef __attribute__((ext_vector_type(8))) short s16x8;

constexpr int BB = 256, TT = 750, NN = 512, INN = 6, OUTN = 2, MLEN = 250;
constexpr int BBLK = 16;                 // batch rows per block (group)
constexpr int NBLKS = BB / BBLK;         // 16 blocks, one per CU
constexpr int WPB = 8;                   // waves per block
constexpr int NSL = NN / WPB;            // 64 neurons per wave
constexpr int NREG = 47;                 // B-frags in registers (of 64)
constexpr int NLDS = 64 - NREG;          // 17 B-frags in LDS per wave
constexpr int HBYTES = BBLK * NN * 2;    // 16 KB h tile (bf16, swizzled)
constexpr int WSTRIDE = NLDS * 1024;     // per-wave LDS weight bytes
constexpr int SMEM_BYTES = HBYTES + WPB * WSTRIDE;  // 155648 B = 152 KB
constexpr float ALPHA_ = 0.2f;

__device__ __forceinline__ unsigned short f2bf(float f) {
    unsigned v = __float_as_uint(f);
    v += 0x7fffu + ((v >> 16) & 1u);     // RNE
    return (unsigned short)(v >> 16);
}
__device__ __forceinline__ float bf2f(unsigned short h) {
    return __uint_as_float(((unsigned)h) << 16);
}

// ---- pre-pass: drv[t][blk][wave][lane][16] bf16 = noise + u @ w_in^T ----
// element e = tt*4 + r within a lane; fully coalesced 32 B/thread writes.
__global__ __launch_bounds__(256)
void drive_kernel(const float* __restrict__ u, const float* __restrict__ noise,
                  const float* __restrict__ w_in, unsigned short* __restrict__ drv)
{
    int gid = blockIdx.x * 256 + threadIdx.x;
    int t = gid >> 13;                           // 16 blk * 8 w * 64 lanes = 8192
    if (t >= TT - 1) return;
    int lane = gid & 63, w = (gid >> 6) & 7, blk = (gid >> 9) & 15;
    int qq = lane >> 4, lr = lane & 15;

    float wv[4][INN];
    #pragma unroll
    for (int tt = 0; tt < 4; ++tt) {
        int n = w * NSL + 16 * tt + lr;
        #pragma unroll
        for (int i = 0; i < INN; ++i) wv[tt][i] = w_in[n * INN + i];
    }
    alignas(16) unsigned short o[16];
    #pragma unroll
    for (int r = 0; r < 4; ++r) {
        int b = blk * BBLK + 4 * qq + r;
        const float* up = u + ((size_t)b * TT + t) * INN;
        float uv[INN];
        #pragma unroll
        for (int i = 0; i < INN; ++i) uv[i] = up[i];
        const float* np = noise + ((size_t)b * TT + t) * NN;
        #pragma unroll
        for (int tt = 0; tt < 4; ++tt) {
            int n = w * NSL + 16 * tt + lr;
            float d = np[n];
            #pragma unroll
            for (int i = 0; i < INN; ++i) d += uv[i] * wv[tt][i];
            o[tt * 4 + r] = f2bf(d);
        }
    }
    s16x8* dst = (s16x8*)(drv + (size_t)gid * 16);
    dst[0] = *(const s16x8*)&o[0];
    dst[1] = *(const s16x8*)&o[8];
}

// ---- persistent scan: 16 blocks x 8 waves, no inter-block traffic ----
__global__ __launch_bounds__(512, 2)
void rnn_scan_kernel(const float* __restrict__ w_rec,
                     const unsigned short* __restrict__ drv,
                     float* __restrict__ states)
{
    extern __shared__ char smem[];
    const int tid = threadIdx.x;
    const int w = tid >> 6, lane = tid & 63;
    const int qq = lane >> 4, lr = lane & 15;
    const int blk = blockIdx.x;
    const int bg = blk * BBLK;

    // stage weights: B-frag (tt,kk): lane holds w_rec[n=64w+16tt+lr][32kk+8qq+j]
    s16x8 breg[NREG];
    #pragma unroll
    for (int tt = 0; tt < 4; ++tt) {
        #pragma unroll
        for (int kk = 0; kk < 16; ++kk) {
            const int f = tt * 16 + kk;
            const int n = w * NSL + 16 * tt + lr;
            const float* p = w_rec + (size_t)n * NN + 32 * kk + 8 * qq;
            f32x4 x0 = *(const f32x4*)p;
            f32x4 x1 = *(const f32x4*)(p + 4);
            union { s16x8 v; unsigned short s[8]; } fr;
            #pragma unroll
            for (int j = 0; j < 4; ++j) { fr.s[j] = f2bf(x0[j]); fr.s[4 + j] = f2bf(x1[j]); }
            if (f < NREG) breg[f] = fr.v;
            else *(s16x8*)(smem + HBYTES + (w * NLDS + (f - NREG)) * 1024 + lane * 16) = fr.v;
        }
    }
    // zero h tile (h_0 = 0) and states[:,0,:] for our rows
    for (int i = tid; i < HBYTES / 4; i += 512) ((unsigned*)smem)[i] = 0u;
    for (int i = tid; i < BBLK * NN; i += 512) {
        int r = i >> 9, n = i & 511;
        states[(size_t)(bg + r) * TT * NN + n] = 0.f;
    }
    __syncthreads();

    float st[4][4];
    #pragma unroll
    for (int tt = 0; tt < 4; ++tt)
        #pragma unroll
        for (int r = 0; r < 4; ++r) st[tt][r] = 0.f;

    const char* hbase = smem + (size_t)lr * 1024;          // A row = lr
    const char* wbase = smem + HBYTES + w * WSTRIDE + lane * 16;
    const int p7 = lr & 7;
    const unsigned short* dbase =
        drv + ((size_t)(blk * WPB + w) * 64 + lane) * 16;

    for (int s = 1; s < TT; ++s) {
        // drive prefetch for this step's epilogue (vmcnt stays in flight
        // across the lgkm-only barrier)
        const s16x8* dp = (const s16x8*)(dbase + (size_t)(s - 1) * (NBLKS * WPB * 64 * 16));
        s16x8 dv0 = dp[0], dv1 = dp[1];

        f32x4 acc[4];
        #pragma unroll
        for (int tt = 0; tt < 4; ++tt) acc[tt] = f32x4{0.f, 0.f, 0.f, 0.f};

        #pragma unroll
        for (int kk = 0; kk < 16; ++kk) {
            // A-frag: h[lr][32kk+8qq+j], XOR-swizzled slot
            s16x8 a = *(const s16x8*)(hbase + (((4 * kk + qq) ^ p7) << 4));
            acc[0] = __builtin_amdgcn_mfma_f32_16x16x32_bf16(a, breg[kk],      acc[0], 0, 0, 0);
            acc[1] = __builtin_amdgcn_mfma_f32_16x16x32_bf16(a, breg[16 + kk], acc[1], 0, 0, 0);
            if (kk < 15)
                acc[2] = __builtin_amdgcn_mfma_f32_16x16x32_bf16(a, breg[32 + kk], acc[2], 0, 0, 0);
            else
                acc[2] = __builtin_amdgcn_mfma_f32_16x16x32_bf16(
                    a, *(const s16x8*)(wbase), acc[2], 0, 0, 0);
            acc[3] = __builtin_amdgcn_mfma_f32_16x16x32_bf16(
                a, *(const s16x8*)(wbase + (kk + 1) * 1024), acc[3], 0, 0, 0);
        }
        // force drive regs resident before barrier (bounded residual wait)
        asm volatile("" : "+v"(dv0), "+v"(dv1));
        // readers done -> writers may proceed; LDS-only drain, vmcnt untouched
        asm volatile("s_waitcnt lgkmcnt(0)\n\ts_barrier" ::: "memory");

        union { s16x8 v; unsigned short e[8]; } u0, u1;
        u0.v = dv0; u1.v = dv1;
        #pragma unroll
        for (int tt = 0; tt < 4; ++tt) {
            #pragma unroll
            for (int r = 0; r < 4; ++r) {
                float d = bf2f(tt < 2 ? u0.e[tt * 4 + r] : u1.e[(tt - 2) * 4 + r]);
                float pre = acc[tt][r] + d;
                float hn = (1.f - ALPHA_) * st[tt][r] + ALPHA_ * fmaxf(pre, 0.f);
                st[tt][r] = hn;
                const int b = bg + 4 * qq + r;
                const int n = w * NSL + 16 * tt + lr;
                states[((size_t)b * TT + s) * NN + n] = hn;
                const int row = 4 * qq + r;
                const int slot = w * 8 + 2 * tt + (lr >> 3);   // n>>3
                *(unsigned short*)(smem + row * 1024 +
                                   (((slot ^ (row & 7)) << 4) | (2 * (lr & 7)))) = f2bf(hn);
            }
        }
        asm volatile("s_waitcnt lgkmcnt(0)\n\ts_barrier" ::: "memory");
    }
}

// out[b,t,o] = sum_n states[b,t,n] * w_out[o,n]; one wave per (b,t) row
__global__ __launch_bounds__(256)
void proj_kernel(const float* __restrict__ states, const float* __restrict__ w_out,
                 float* __restrict__ outf)
{
    const int wv   = (blockIdx.x * blockDim.x + threadIdx.x) >> 6;
    const int lane = threadIdx.x & 63;
    const float* sp = states + (size_t)wv * NN + lane * 8;
    const float* w0 = w_out + lane * 8;
    const float* w1 = w_out + NN + lane * 8;
    float d0 = 0.f, d1 = 0.f;
    #pragma unroll
    for (int i = 0; i < 8; ++i) {
        float sv = sp[i];
        d0 += sv * w0[i];
        d1 += sv * w1[i];
    }
    #pragma unroll
    for (int off = 32; off > 0; off >>= 1) {
        d0 += __shfl_xor(d0, off);
        d1 += __shfl_xor(d1, off);
    }
    if (lane == 0) {
        outf[(size_t)wv * 2]     = d0;
        outf[(size_t)wv * 2 + 1] = d1;
    }
}

__global__ void mask_kernel(const int* __restrict__ mask, const float* __restrict__ outf,
                            float* __restrict__ outm)
{
    int idx = blockIdx.x * blockDim.x + threadIdx.x;
    if (idx >= BB * MLEN * OUTN) return;
    int o  = idx % OUTN;
    int jm = (idx / OUTN) % MLEN;
    int b  = idx / (OUTN * MLEN);
    int t  = mask[jm];
    outm[idx] = outf[((size_t)b * TT + t) * OUTN + o];
}

extern "C" void kernel_launch(void* const* d_in, const int* in_sizes, int n_in,
                              void* d_out, int out_size, void* d_ws, size_t ws_size,
                              hipStream_t stream)
{
    (void)in_sizes; (void)n_in; (void)out_size; (void)ws_size;
    const float* u     = (const float*)d_in[0];
    const float* noise = (const float*)d_in[1];
    const float* w_rec = (const float*)d_in[2];
    const float* w_in  = (const float*)d_in[3];
    const float* w_out = (const float*)d_in[4];
    const int*   mask  = (const int*)d_in[5];

    float* states = (float*)d_out;                          // [256][750][512]
    float* outm   = states + (size_t)BB * TT * NN;          // [256][250][2]
    float* outf   = outm + (size_t)BB * MLEN * OUTN;        // [256][750][2]

    unsigned short* drvpk = (unsigned short*)d_ws;          // 749*16*8*64*16 bf16 = 196.3 MB

    hipFuncSetAttribute((const void*)rnn_scan_kernel,
                        hipFuncAttributeMaxDynamicSharedMemorySize, SMEM_BYTES);

    drive_kernel<<<(TT - 1) * 32, 256, 0, stream>>>(u, noise, w_in, drvpk);
    rnn_scan_kernel<<<NBLKS, 512, SMEM_BYTES, stream>>>(w_rec, drvpk, states);
    proj_kernel<<<(BB * TT) / 4, 256, 0, stream>>>(states, w_out, outf);
    mask_kernel<<<(BB * MLEN * OUTN + 255) / 256, 256, 0, stream>>>(mask, outf, outm);
}